// Round 10
// baseline (66.039 us; speedup 1.0000x reference)
//
#include <hip/hip_runtime.h>
#include <math.h>

#define HWSZ 36864            // 192*192
#define NWID 2304             // 32-px tiles (2 images * 1152)

typedef short bf16x8 __attribute__((ext_vector_type(8)));
typedef float f32x16 __attribute__((ext_vector_type(16)));
typedef unsigned int u32x4 __attribute__((ext_vector_type(4)));

__device__ __forceinline__ unsigned short f2bf(float x) {
    unsigned u = __float_as_uint(x);
    return (unsigned short)((u + 0x7fffu + ((u >> 16) & 1u)) >> 16);  // RNE
}

// barrier that does NOT drain vmcnt: in-flight global loads survive (T4)
__device__ __forceinline__ void block_sync_lds() {
    __builtin_amdgcn_sched_barrier(0);
    asm volatile("s_waitcnt lgkmcnt(0)" ::: "memory");
    __builtin_amdgcn_s_barrier();
    __builtin_amdgcn_sched_barrier(0);
}

// ---------------- single precompute kernel: weights folded straight into
// MFMA A-fragments (bf16). AfragW [s][r(4)][kt(4)][lane(64)][e(8)]:
//   r<2: D_s rows (delta), r>=2: MT_s rows (h).  AfragMS2 [r(2)][kt][lane][e]:
//   MS2 = MSp - sum_s MT_s  (h = c1 + MS2*S + sum_s MT_s*T_s).
__global__ void pre_all(const float* __restrict__ rw1, const float* __restrict__ rb1,
                        const float* __restrict__ aw, const float* __restrict__ ab,
                        const float* __restrict__ mu, const float* __restrict__ sg,
                        unsigned short* __restrict__ AfragW,
                        unsigned short* __restrict__ AfragMS2, float* __restrict__ c1) {
    int i = blockIdx.x * 256 + threadIdx.x;
    if (i < 40960) {
        int s = i / 8192, rem = i % 8192;
        int r = rem / 2048, rem2 = rem % 2048;
        int t = rem2 / 512, q = rem2 % 512;
        int l = q >> 3, e = q & 7;
        int R = 32 * r + (l & 31);
        int k = 16 * t + 8 * (l >> 5) + e;
        float v;
        if (R < 64) {
            v = aw[s * 4096 + R * 64 + k] / sg[s * 64 + R];        // D_s[R][k]
        } else {
            int o = R - 64;                                        // MT_s[o][k]
            const float* wp = rw1 + o * 960 + s * 192;
            const float* A  = aw + s * 4096 + k;
            const float* G  = sg + s * 64;
            float sum = 0.f;
            #pragma unroll 8
            for (int d = 0; d < 64; ++d)
                sum = fmaf(wp[64 + d] + wp[128 + d], A[d * 64] / G[d], sum);
            v = sum;
        }
        AfragW[i] = f2bf(v);
    } else if (i < 45056) {
        int j = i - 40960;
        int r = j / 2048, rem2 = j % 2048;
        int t = rem2 / 512, q = rem2 % 512;
        int l = q >> 3, e = q & 7;
        int o = 32 * r + (l & 31);
        int k = 16 * t + 8 * (l >> 5) + e;
        float sum = 0.f;
        for (int s = 0; s < 5; ++s) {
            const float* wp = rw1 + o * 960 + s * 192;
            const float* A  = aw + s * 4096 + k;
            const float* G  = sg + s * 64;
            #pragma unroll 8
            for (int d = 0; d < 64; ++d)
                sum = fmaf(wp[d] - wp[128 + d], A[d * 64] / G[d], sum);
        }
        AfragMS2[j] = f2bf(sum);
    } else if (i < 45120) {
        int o = i - 45056;
        float sum = rb1[o];
        for (int s = 0; s < 5; ++s) {
            const float* wp = rw1 + o * 960 + s * 192;
            #pragma unroll 8
            for (int d = 0; d < 64; ++d) {
                int sd = s * 64 + d;
                sum = fmaf(wp[d] + wp[64 + d], (ab[sd] - mu[sd]) / sg[sd], sum);
            }
        }
        c1[o] = sum;
    }
}

// ---------------- fused main: 2 waves / 32 px, 8 blocks/CU (~50% occupancy),
// balanced wave split (wave w = row-half w of D/MT/MS2), S-fragments in regs,
// delta = D*T - D*S, lgkm-only barriers, 1-deep T prefetch.
__global__ __launch_bounds__(128, 4) void fused_main(
        const float* __restrict__ S, const float* __restrict__ T,
        const unsigned short* __restrict__ AfragW, const unsigned short* __restrict__ AfragMS2,
        const float* __restrict__ c1, const float* __restrict__ rw2, const float* __restrict__ rb2,
        float* __restrict__ slearn, float* __restrict__ partial) {
    // frag-order tile: u16 idx ((kt*2+hh)*32 + slot(px))*8 + e ; 4 KB each
    __shared__ __align__(16) unsigned short sTile[2048];
    __shared__ __align__(16) unsigned short tbuf[2][2048];
    __shared__ float w2s[320];
    __shared__ float c1s[64];
    __shared__ float rb2s[8];
    __shared__ float wred[5][2];
    __shared__ float hpart[2][5][32];

    const int tid = threadIdx.x, lane = tid & 63, w = tid >> 6;   // w = 0,1
    const int hi = lane >> 5, pxm = lane & 31;
    const int blk = blockIdx.x;
    const int b = blk / 1152;
    const int pix0 = (blk % 1152) * 32;

    // staging map: thread = (ch octet o8 0..7, px pair pq 0..15)
    const int o8 = tid >> 4, pq = tid & 15;
    const float* Sp = S + ((size_t)(b * 64 + 8 * o8)) * HWSZ + pix0 + 2 * pq;
    const float* Tp = T + ((size_t)(b * 5 * 64 + 8 * o8)) * HWSZ + pix0 + 2 * pq;

    // issue S then T0 immediately
    float2 RS[8], R[8];
    #pragma unroll
    for (int j = 0; j < 8; ++j) RS[j] = *(const float2*)(Sp + (size_t)j * HWSZ);
    #pragma unroll
    for (int j = 0; j < 8; ++j) R[j] = *(const float2*)(Tp + (size_t)j * HWSZ);

    for (int i = tid; i < 320; i += 128) w2s[i] = rw2[i];
    if (tid < 64) c1s[tid] = c1[tid];
    if (tid < 5)  rb2s[tid] = rb2[tid];

    // bijective slot swizzle: spreads the 512B-chunked write pattern across banks
    auto slot = [](int px) { return px ^ (px >> 3); };

    auto packWrite = [&](unsigned short* dst, const float2* Rv) {
        #pragma unroll
        for (int pi = 0; pi < 2; ++pi) {
            int px = 2 * pq + pi;
            u32x4 v;
            #pragma unroll
            for (int jj = 0; jj < 4; ++jj) {
                float a = pi ? Rv[2 * jj].y : Rv[2 * jj].x;
                float c = pi ? Rv[2 * jj + 1].y : Rv[2 * jj + 1].x;
                v[jj] = (unsigned)f2bf(a) | ((unsigned)f2bf(c) << 16);
            }
            *(u32x4*)&dst[(o8 * 32 + slot(px)) * 8] = v;
        }
    };
    auto loadT = [&](float2* Rv, int s) {
        const float* p = Tp + (size_t)(s * 64) * HWSZ;
        #pragma unroll
        for (int j = 0; j < 8; ++j) Rv[j] = *(const float2*)(p + (size_t)j * HWSZ);
    };
    auto ldsB = [&](const unsigned short* buf, int kt) -> bf16x8 {
        return *(const bf16x8*)&buf[((kt * 2 + hi) * 32 + slot(pxm)) * 8];
    };

    // MS2 fragments (rowtile w) — issued during S-pack window
    const bf16x8* am = (const bf16x8*)AfragMS2 + lane;
    bf16x8 msf[4];
    #pragma unroll
    for (int kt = 0; kt < 4; ++kt) msf[kt] = am[(w * 4 + kt) * 64];

    packWrite(sTile, RS);      // waits on S loads only
    block_sync_lds();          // sTile visible

    // S-side B-fragments: loaded ONCE, register-resident for all 6 GEMM uses
    bf16x8 bS[4];
    #pragma unroll
    for (int kt = 0; kt < 4; ++kt) bS[kt] = ldsB(sTile, kt);

    f32x16 hacc;
    #pragma unroll
    for (int i = 0; i < 16; ++i) hacc[i] = 0.f;
    #pragma unroll
    for (int kt = 0; kt < 4; ++kt)
        hacc = __builtin_amdgcn_mfma_f32_32x32x16_bf16(msf[kt], bS[kt], hacc, 0, 0, 0);

    packWrite(tbuf[0], R);     // stage T0 (R resident since prologue)
    loadT(R, 1);               // T1 in flight across s=0
    block_sync_lds();

    const bf16x8* afw = (const bf16x8*)AfragW + lane;

    #pragma unroll
    for (int s = 0; s < 5; ++s) {
        const unsigned short* cur = tbuf[s & 1];
        unsigned short* nxt = tbuf[(s + 1) & 1];

        // weight fragments for this s (L2-hot, ~1KB each)
        bf16x8 fD[4], fM[4];
        #pragma unroll
        for (int kt = 0; kt < 4; ++kt) fD[kt] = afw[((s * 4 + w) * 4 + kt) * 64];
        #pragma unroll
        for (int kt = 0; kt < 4; ++kt) fM[kt] = afw[((s * 4 + 2 + w) * 4 + kt) * 64];

        if (s < 4) {
            packWrite(nxt, R);          // T_{s+1}, regs resident ~1 iter
            if (s < 3) loadT(R, s + 2);
        }

        // delta = D_s*T - D_s*S : S-side from register fragments
        f32x16 dacc;
        #pragma unroll
        for (int i = 0; i < 16; ++i) dacc[i] = 0.f;
        #pragma unroll
        for (int kt = 0; kt < 4; ++kt)
            dacc = __builtin_amdgcn_mfma_f32_32x32x16_bf16(fD[kt], bS[kt], dacc, 0, 0, 0);
        #pragma unroll
        for (int i = 0; i < 16; ++i) dacc[i] = -dacc[i];
        #pragma unroll
        for (int kt = 0; kt < 4; ++kt) {
            bf16x8 bT = ldsB(cur, kt);
            dacc = __builtin_amdgcn_mfma_f32_32x32x16_bf16(fD[kt], bT, dacc, 0, 0, 0);
            hacc = __builtin_amdgcn_mfma_f32_32x32x16_bf16(fM[kt], bT, hacc, 0, 0, 0);
        }

        float sq = 0.f;
        #pragma unroll
        for (int i = 0; i < 16; ++i) sq = fmaf(dacc[i], dacc[i], sq);
        #pragma unroll
        for (int m = 1; m < 64; m <<= 1) sq += __shfl_xor(sq, m, 64);
        if (lane == 0) wred[s][w] = sq;

        block_sync_lds();
    }

    // ---- epilogue: relu(h+c1), w2 dot, combine halves via LDS ----
    #pragma unroll
    for (int i = 0; i < 16; ++i) {
        int row = (i & 3) + 8 * (i >> 2) + 4 * hi + 32 * w;
        hacc[i] = fmaxf(hacc[i] + c1s[row], 0.f);
    }
    #pragma unroll
    for (int sp = 0; sp < 5; ++sp) {
        float d = 0.f;
        #pragma unroll
        for (int i = 0; i < 16; ++i) {
            int row = (i & 3) + 8 * (i >> 2) + 4 * hi + 32 * w;
            d = fmaf(w2s[sp * 64 + row], hacc[i], d);
        }
        d += __shfl_xor(d, 32, 64);
        if (hi == 0) hpart[w][sp][pxm] = d;
    }
    block_sync_lds();
    if (tid < 5) partial[blk * 5 + tid] = wred[tid][0] + wred[tid][1];
    for (int i = tid; i < 160; i += 128) {
        int sp = i >> 5, px = i & 31;
        slearn[((size_t)(b * 5 + sp)) * HWSZ + pix0 + px] =
            hpart[0][sp][px] + hpart[1][sp][px] + rb2s[sp];
    }
}

// ---------------- reduce proxy partials -> per-s score (deterministic)
__global__ void score_kernel(const float* __restrict__ partial,
                             const float* __restrict__ ema_proxy,
                             float* __restrict__ scoreBuf) {
    __shared__ float red[256];
    __shared__ float cur[5];
    int tid = threadIdx.x;
    for (int s = 0; s < 5; ++s) {
        float sum = 0.f;
        for (int i = tid; i < NWID; i += 256) sum += partial[i * 5 + s];
        red[tid] = sum;
        __syncthreads();
        for (int off = 128; off > 0; off >>= 1) {
            if (tid < off) red[tid] += red[tid + off];
            __syncthreads();
        }
        if (tid == 0) cur[s] = red[0] * (1.0f / (64.0f * 2.0f * HWSZ));
        __syncthreads();
    }
    if (tid == 0) {
        float impr[5]; float m = 0.f;
        for (int s = 0; s < 5; ++s) { impr[s] = ema_proxy[s] - cur[s]; m += impr[s]; }
        m *= 0.2f;
        for (int s = 0; s < 5; ++s) {
            float adv = impr[s] - m;
            float c = cur[s];
            float below = fmaxf(0.05f - c, 0.f);
            float above = fmaxf(c - 0.2f, 0.f);
            float band = -(below * below + above * above);
            scoreBuf[s] = 1.0f * adv + 0.5f * band;
        }
    }
}

// ---------------- per-pixel softmax over Sn=5
__global__ void softmax_kernel(const float* __restrict__ slearn,
                               const float* __restrict__ scoreBuf,
                               float* __restrict__ out) {
    int i = blockIdx.x * 256 + threadIdx.x;
    if (i >= 2 * HWSZ) return;
    int b = i / HWSZ, p = i % HWSZ;
    float l[5];
    float mx = -1e30f;
    #pragma unroll
    for (int s = 0; s < 5; ++s) {
        float v = (0.5f * scoreBuf[s] + 0.5f * slearn[((size_t)(b * 5 + s)) * HWSZ + p]) / 0.7f;
        l[s] = v;
        mx = fmaxf(mx, v);
    }
    float sum = 0.f;
    #pragma unroll
    for (int s = 0; s < 5; ++s) { l[s] = expf(l[s] - mx); sum += l[s]; }
    float inv = 1.0f / sum;
    #pragma unroll
    for (int s = 0; s < 5; ++s) out[((size_t)(b * 5 + s)) * HWSZ + p] = l[s] * inv;
}

extern "C" void kernel_launch(void* const* d_in, const int* in_sizes, int n_in,
                              void* d_out, int out_size, void* d_ws, size_t ws_size,
                              hipStream_t stream) {
    const float* S   = (const float*)d_in[0];
    const float* T   = (const float*)d_in[1];
    const float* aw  = (const float*)d_in[2];
    const float* ab  = (const float*)d_in[3];
    const float* rw1 = (const float*)d_in[4];
    const float* rb1 = (const float*)d_in[5];
    const float* rw2 = (const float*)d_in[6];
    const float* rb2 = (const float*)d_in[7];
    const float* mu  = (const float*)d_in[8];
    const float* sg  = (const float*)d_in[9];
    const float* ep  = (const float*)d_in[10];

    float* ws = (float*)d_ws;
    float* c1f      = ws;                                       // 64
    float* scoreBuf = ws + 64;                                  // 8
    float* partial  = ws + 72;                                  // 11520 (2304*5)
    unsigned short* AfragW   = (unsigned short*)(ws + 11592);   // 40960 u16
    unsigned short* AfragMS2 = (unsigned short*)(ws + 32072);   // 4096 u16
    float* slearn   = ws + 34120;                               // 368640
    float* out = (float*)d_out;

    pre_all<<<177, 256, 0, stream>>>(rw1, rb1, aw, ab, mu, sg, AfragW, AfragMS2, c1f);
    fused_main<<<NWID, 128, 0, stream>>>(S, T, AfragW, AfragMS2, c1f, rw2, rb2, slearn, partial);
    score_kernel<<<1, 256, 0, stream>>>(partial, ep, scoreBuf);
    softmax_kernel<<<288, 256, 0, stream>>>(slearn, scoreBuf, out);
}

// Round 11
// 63.514 us; speedup vs baseline: 1.0398x; 1.0398x over previous
//
#include <hip/hip_runtime.h>
#include <math.h>

#define HWSZ 36864            // 192*192
#define NWID 2304             // proxy partial tiles (2 per block)
#define NBLK6 1152            // blocks: 2 images * 576 * (64px / block, 2 tiles)

typedef short bf16x8 __attribute__((ext_vector_type(8)));
typedef float f32x16 __attribute__((ext_vector_type(16)));
typedef unsigned int u32x4 __attribute__((ext_vector_type(4)));

__device__ __forceinline__ unsigned short f2bf(float x) {
    unsigned u = __float_as_uint(x);
    return (unsigned short)((u + 0x7fffu + ((u >> 16) & 1u)) >> 16);  // RNE
}

// barrier that does NOT drain vmcnt: in-flight global loads survive (T4)
__device__ __forceinline__ void block_sync_lds() {
    __builtin_amdgcn_sched_barrier(0);
    asm volatile("s_waitcnt lgkmcnt(0)" ::: "memory");
    __builtin_amdgcn_s_barrier();
    __builtin_amdgcn_sched_barrier(0);
}

// ---------------- single precompute kernel (unchanged from r7-r10)
__global__ void pre_all(const float* __restrict__ rw1, const float* __restrict__ rb1,
                        const float* __restrict__ aw, const float* __restrict__ ab,
                        const float* __restrict__ mu, const float* __restrict__ sg,
                        unsigned short* __restrict__ AfragW,
                        unsigned short* __restrict__ AfragMS2, float* __restrict__ c1) {
    int i = blockIdx.x * 256 + threadIdx.x;
    if (i < 40960) {
        int s = i / 8192, rem = i % 8192;
        int r = rem / 2048, rem2 = rem % 2048;
        int t = rem2 / 512, q = rem2 % 512;
        int l = q >> 3, e = q & 7;
        int R = 32 * r + (l & 31);
        int k = 16 * t + 8 * (l >> 5) + e;
        float v;
        if (R < 64) {
            v = aw[s * 4096 + R * 64 + k] / sg[s * 64 + R];        // D_s[R][k]
        } else {
            int o = R - 64;                                        // MT_s[o][k]
            const float* wp = rw1 + o * 960 + s * 192;
            const float* A  = aw + s * 4096 + k;
            const float* G  = sg + s * 64;
            float sum = 0.f;
            #pragma unroll 8
            for (int d = 0; d < 64; ++d)
                sum = fmaf(wp[64 + d] + wp[128 + d], A[d * 64] / G[d], sum);
            v = sum;
        }
        AfragW[i] = f2bf(v);
    } else if (i < 45056) {
        int j = i - 40960;
        int r = j / 2048, rem2 = j % 2048;
        int t = rem2 / 512, q = rem2 % 512;
        int l = q >> 3, e = q & 7;
        int o = 32 * r + (l & 31);
        int k = 16 * t + 8 * (l >> 5) + e;
        float sum = 0.f;
        for (int s = 0; s < 5; ++s) {
            const float* wp = rw1 + o * 960 + s * 192;
            const float* A  = aw + s * 4096 + k;
            const float* G  = sg + s * 64;
            #pragma unroll 8
            for (int d = 0; d < 64; ++d)
                sum = fmaf(wp[d] - wp[128 + d], A[d * 64] / G[d], sum);
        }
        AfragMS2[j] = f2bf(sum);
    } else if (i < 45120) {
        int o = i - 45056;
        float sum = rb1[o];
        for (int s = 0; s < 5; ++s) {
            const float* wp = rw1 + o * 960 + s * 192;
            #pragma unroll 8
            for (int d = 0; d < 64; ++d) {
                int sd = s * 64 + d;
                sum = fmaf(wp[d] + wp[64 + d], (ab[sd] - mu[sd]) / sg[sd], sum);
            }
        }
        c1[o] = sum;
    }
}

// ---------------- fused main: 2 waves / block, TWO independent 32-px tiles
// per block (iteration length ~2x load latency), balanced wave split,
// S-fragments register-resident, delta = D*T - D*S, lgkm-only barriers,
// weights double-buffered one s ahead.
__global__ __launch_bounds__(128, 2) void fused_main(
        const float* __restrict__ S, const float* __restrict__ T,
        const unsigned short* __restrict__ AfragW, const unsigned short* __restrict__ AfragMS2,
        const float* __restrict__ c1, const float* __restrict__ rw2, const float* __restrict__ rb2,
        float* __restrict__ slearn, float* __restrict__ partial) {
    __shared__ __align__(16) unsigned short sTileA[2048], sTileB[2048];
    __shared__ __align__(16) unsigned short tbufA[2][2048], tbufB[2][2048];
    __shared__ float w2s[320];
    __shared__ float c1s[64];
    __shared__ float rb2s[8];
    __shared__ float wredA[5][2], wredB[5][2];
    __shared__ float hpartA[2][5][32], hpartB[2][5][32];

    const int tid = threadIdx.x, lane = tid & 63, w = tid >> 6;   // w = 0,1
    const int hi = lane >> 5, pxm = lane & 31;
    const int blk = blockIdx.x;
    const int b = blk / 576;
    const int pix0 = (blk % 576) * 64;

    // staging map: thread = (ch octet o8 0..7, px pair pq 0..15)
    const int o8 = tid >> 4, pq = tid & 15;
    const float* SpA = S + ((size_t)(b * 64 + 8 * o8)) * HWSZ + pix0 + 2 * pq;
    const float* TpA = T + ((size_t)(b * 5 * 64 + 8 * o8)) * HWSZ + pix0 + 2 * pq;
    const float* SpB = SpA + 32;
    const float* TpB = TpA + 32;

    // issue S_A, S_B, T0_A, T0_B: 32 loads in flight before any consume
    float2 RSA[8], RSB[8], RA[8], RB[8];
    #pragma unroll
    for (int j = 0; j < 8; ++j) RSA[j] = *(const float2*)(SpA + (size_t)j * HWSZ);
    #pragma unroll
    for (int j = 0; j < 8; ++j) RSB[j] = *(const float2*)(SpB + (size_t)j * HWSZ);
    #pragma unroll
    for (int j = 0; j < 8; ++j) RA[j] = *(const float2*)(TpA + (size_t)j * HWSZ);
    #pragma unroll
    for (int j = 0; j < 8; ++j) RB[j] = *(const float2*)(TpB + (size_t)j * HWSZ);

    for (int i = tid; i < 320; i += 128) w2s[i] = rw2[i];
    if (tid < 64) c1s[tid] = c1[tid];
    if (tid < 5)  rb2s[tid] = rb2[tid];

    // bijective slot swizzle (r10: 0 bank conflicts)
    auto slot = [](int px) { return px ^ (px >> 3); };

    auto packWrite = [&](unsigned short* dst, const float2* Rv) {
        #pragma unroll
        for (int pi = 0; pi < 2; ++pi) {
            int px = 2 * pq + pi;
            u32x4 v;
            #pragma unroll
            for (int jj = 0; jj < 4; ++jj) {
                float a = pi ? Rv[2 * jj].y : Rv[2 * jj].x;
                float c = pi ? Rv[2 * jj + 1].y : Rv[2 * jj + 1].x;
                v[jj] = (unsigned)f2bf(a) | ((unsigned)f2bf(c) << 16);
            }
            *(u32x4*)&dst[(o8 * 32 + slot(px)) * 8] = v;
        }
    };
    auto loadT = [&](float2* Rv, const float* Tp_, int s) {
        const float* p = Tp_ + (size_t)(s * 64) * HWSZ;
        #pragma unroll
        for (int j = 0; j < 8; ++j) Rv[j] = *(const float2*)(p + (size_t)j * HWSZ);
    };
    auto ldsB = [&](const unsigned short* buf, int kt) -> bf16x8 {
        return *(const bf16x8*)&buf[((kt * 2 + hi) * 32 + slot(pxm)) * 8];
    };

    // MS2 fragments (rowtile w) + s=0 weight fragments, issued under S-load window
    const bf16x8* am = (const bf16x8*)AfragMS2 + lane;
    bf16x8 msf[4];
    #pragma unroll
    for (int kt = 0; kt < 4; ++kt) msf[kt] = am[(w * 4 + kt) * 64];

    const bf16x8* afw = (const bf16x8*)AfragW + lane;
    bf16x8 fD0[4], fM0[4], fD1[4], fM1[4];
    #pragma unroll
    for (int kt = 0; kt < 4; ++kt) fD0[kt] = afw[((0 * 4 + w) * 4 + kt) * 64];
    #pragma unroll
    for (int kt = 0; kt < 4; ++kt) fM0[kt] = afw[((0 * 4 + 2 + w) * 4 + kt) * 64];

    packWrite(sTileA, RSA);     // waits on S loads only (vmcnt counted)
    packWrite(sTileB, RSB);
    block_sync_lds();           // S tiles visible

    // S-side B-fragments: register-resident for all 12 GEMM uses
    bf16x8 bSA[4], bSB[4];
    #pragma unroll
    for (int kt = 0; kt < 4; ++kt) { bSA[kt] = ldsB(sTileA, kt); bSB[kt] = ldsB(sTileB, kt); }

    f32x16 hA, hB;
    #pragma unroll
    for (int i = 0; i < 16; ++i) { hA[i] = 0.f; hB[i] = 0.f; }
    #pragma unroll
    for (int kt = 0; kt < 4; ++kt) {
        hA = __builtin_amdgcn_mfma_f32_32x32x16_bf16(msf[kt], bSA[kt], hA, 0, 0, 0);
        hB = __builtin_amdgcn_mfma_f32_32x32x16_bf16(msf[kt], bSB[kt], hB, 0, 0, 0);
    }

    packWrite(tbufA[0], RA);    // stage T0 (regs resident since prologue)
    packWrite(tbufB[0], RB);
    loadT(RA, TpA, 1);          // T1 in flight across s=0
    loadT(RB, TpB, 1);
    block_sync_lds();

    #pragma unroll
    for (int s = 0; s < 5; ++s) {
        const unsigned short* curA = tbufA[s & 1];
        unsigned short* nxtA       = tbufA[(s + 1) & 1];
        const unsigned short* curB = tbufB[s & 1];
        unsigned short* nxtB       = tbufB[(s + 1) & 1];
        const bf16x8* fDc = (s & 1) ? fD1 : fD0;
        const bf16x8* fMc = (s & 1) ? fM1 : fM0;
        bf16x8* fDn = (s & 1) ? fD0 : fD1;
        bf16x8* fMn = (s & 1) ? fM0 : fM1;

        if (s < 4) {
            // prefetch next-s weights (L2) and stage next-s T tiles
            #pragma unroll
            for (int kt = 0; kt < 4; ++kt) fDn[kt] = afw[(((s + 1) * 4 + w) * 4 + kt) * 64];
            #pragma unroll
            for (int kt = 0; kt < 4; ++kt) fMn[kt] = afw[(((s + 1) * 4 + 2 + w) * 4 + kt) * 64];
            packWrite(nxtA, RA);
            packWrite(nxtB, RB);
            if (s < 3) { loadT(RA, TpA, s + 2); loadT(RB, TpB, s + 2); }
        }

        // ---- tile A ----
        {
            f32x16 dacc;
            #pragma unroll
            for (int i = 0; i < 16; ++i) dacc[i] = 0.f;
            #pragma unroll
            for (int kt = 0; kt < 4; ++kt)
                dacc = __builtin_amdgcn_mfma_f32_32x32x16_bf16(fDc[kt], bSA[kt], dacc, 0, 0, 0);
            #pragma unroll
            for (int i = 0; i < 16; ++i) dacc[i] = -dacc[i];
            #pragma unroll
            for (int kt = 0; kt < 4; ++kt) {
                bf16x8 bT = ldsB(curA, kt);
                dacc = __builtin_amdgcn_mfma_f32_32x32x16_bf16(fDc[kt], bT, dacc, 0, 0, 0);
                hA   = __builtin_amdgcn_mfma_f32_32x32x16_bf16(fMc[kt], bT, hA, 0, 0, 0);
            }
            float sq = 0.f;
            #pragma unroll
            for (int i = 0; i < 16; ++i) sq = fmaf(dacc[i], dacc[i], sq);
            #pragma unroll
            for (int m = 1; m < 64; m <<= 1) sq += __shfl_xor(sq, m, 64);
            if (lane == 0) wredA[s][w] = sq;
        }
        // ---- tile B ----
        {
            f32x16 dacc;
            #pragma unroll
            for (int i = 0; i < 16; ++i) dacc[i] = 0.f;
            #pragma unroll
            for (int kt = 0; kt < 4; ++kt)
                dacc = __builtin_amdgcn_mfma_f32_32x32x16_bf16(fDc[kt], bSB[kt], dacc, 0, 0, 0);
            #pragma unroll
            for (int i = 0; i < 16; ++i) dacc[i] = -dacc[i];
            #pragma unroll
            for (int kt = 0; kt < 4; ++kt) {
                bf16x8 bT = ldsB(curB, kt);
                dacc = __builtin_amdgcn_mfma_f32_32x32x16_bf16(fDc[kt], bT, dacc, 0, 0, 0);
                hB   = __builtin_amdgcn_mfma_f32_32x32x16_bf16(fMc[kt], bT, hB, 0, 0, 0);
            }
            float sq = 0.f;
            #pragma unroll
            for (int i = 0; i < 16; ++i) sq = fmaf(dacc[i], dacc[i], sq);
            #pragma unroll
            for (int m = 1; m < 64; m <<= 1) sq += __shfl_xor(sq, m, 64);
            if (lane == 0) wredB[s][w] = sq;
        }
        block_sync_lds();
    }

    // ---- epilogue: relu(h+c1), w2 dot, combine halves via LDS ----
    #pragma unroll
    for (int i = 0; i < 16; ++i) {
        int row = (i & 3) + 8 * (i >> 2) + 4 * hi + 32 * w;
        hA[i] = fmaxf(hA[i] + c1s[row], 0.f);
        hB[i] = fmaxf(hB[i] + c1s[row], 0.f);
    }
    #pragma unroll
    for (int sp = 0; sp < 5; ++sp) {
        float dA = 0.f, dB = 0.f;
        #pragma unroll
        for (int i = 0; i < 16; ++i) {
            int row = (i & 3) + 8 * (i >> 2) + 4 * hi + 32 * w;
            dA = fmaf(w2s[sp * 64 + row], hA[i], dA);
            dB = fmaf(w2s[sp * 64 + row], hB[i], dB);
        }
        dA += __shfl_xor(dA, 32, 64);
        dB += __shfl_xor(dB, 32, 64);
        if (hi == 0) { hpartA[w][sp][pxm] = dA; hpartB[w][sp][pxm] = dB; }
    }
    block_sync_lds();
    if (tid < 5) {
        partial[(blk * 2 + 0) * 5 + tid] = wredA[tid][0] + wredA[tid][1];
    } else if (tid < 10) {
        int t5 = tid - 5;
        partial[(blk * 2 + 1) * 5 + t5] = wredB[t5][0] + wredB[t5][1];
    }
    for (int i = tid; i < 320; i += 128) {
        int sp = i >> 6, px = i & 63;
        float v = (px < 32) ? (hpartA[0][sp][px] + hpartA[1][sp][px])
                            : (hpartB[0][sp][px - 32] + hpartB[1][sp][px - 32]);
        slearn[((size_t)(b * 5 + sp)) * HWSZ + pix0 + px] = v + rb2s[sp];
    }
}

// ---------------- reduce proxy partials -> per-s score (deterministic)
__global__ void score_kernel(const float* __restrict__ partial,
                             const float* __restrict__ ema_proxy,
                             float* __restrict__ scoreBuf) {
    __shared__ float red[256];
    __shared__ float cur[5];
    int tid = threadIdx.x;
    for (int s = 0; s < 5; ++s) {
        float sum = 0.f;
        for (int i = tid; i < NWID; i += 256) sum += partial[i * 5 + s];
        red[tid] = sum;
        __syncthreads();
        for (int off = 128; off > 0; off >>= 1) {
            if (tid < off) red[tid] += red[tid + off];
            __syncthreads();
        }
        if (tid == 0) cur[s] = red[0] * (1.0f / (64.0f * 2.0f * HWSZ));
        __syncthreads();
    }
    if (tid == 0) {
        float impr[5]; float m = 0.f;
        for (int s = 0; s < 5; ++s) { impr[s] = ema_proxy[s] - cur[s]; m += impr[s]; }
        m *= 0.2f;
        for (int s = 0; s < 5; ++s) {
            float adv = impr[s] - m;
            float c = cur[s];
            float below = fmaxf(0.05f - c, 0.f);
            float above = fmaxf(c - 0.2f, 0.f);
            float band = -(below * below + above * above);
            scoreBuf[s] = 1.0f * adv + 0.5f * band;
        }
    }
}

// ---------------- per-pixel softmax over Sn=5
__global__ void softmax_kernel(const float* __restrict__ slearn,
                               const float* __restrict__ scoreBuf,
                               float* __restrict__ out) {
    int i = blockIdx.x * 256 + threadIdx.x;
    if (i >= 2 * HWSZ) return;
    int b = i / HWSZ, p = i % HWSZ;
    float l[5];
    float mx = -1e30f;
    #pragma unroll
    for (int s = 0; s < 5; ++s) {
        float v = (0.5f * scoreBuf[s] + 0.5f * slearn[((size_t)(b * 5 + s)) * HWSZ + p]) / 0.7f;
        l[s] = v;
        mx = fmaxf(mx, v);
    }
    float sum = 0.f;
    #pragma unroll
    for (int s = 0; s < 5; ++s) { l[s] = expf(l[s] - mx); sum += l[s]; }
    float inv = 1.0f / sum;
    #pragma unroll
    for (int s = 0; s < 5; ++s) out[((size_t)(b * 5 + s)) * HWSZ + p] = l[s] * inv;
}

extern "C" void kernel_launch(void* const* d_in, const int* in_sizes, int n_in,
                              void* d_out, int out_size, void* d_ws, size_t ws_size,
                              hipStream_t stream) {
    const float* S   = (const float*)d_in[0];
    const float* T   = (const float*)d_in[1];
    const float* aw  = (const float*)d_in[2];
    const float* ab  = (const float*)d_in[3];
    const float* rw1 = (const float*)d_in[4];
    const float* rb1 = (const float*)d_in[5];
    const float* rw2 = (const float*)d_in[6];
    const float* rb2 = (const float*)d_in[7];
    const float* mu  = (const float*)d_in[8];
    const float* sg  = (const float*)d_in[9];
    const float* ep  = (const float*)d_in[10];

    float* ws = (float*)d_ws;
    float* c1f      = ws;                                       // 64
    float* scoreBuf = ws + 64;                                  // 8
    float* partial  = ws + 72;                                  // 11520 (2304*5)
    unsigned short* AfragW   = (unsigned short*)(ws + 11592);   // 40960 u16
    unsigned short* AfragMS2 = (unsigned short*)(ws + 32072);   // 4096 u16
    float* slearn   = ws + 34120;                               // 368640
    float* out = (float*)d_out;

    pre_all<<<177, 256, 0, stream>>>(rw1, rb1, aw, ab, mu, sg, AfragW, AfragMS2, c1f);
    fused_main<<<NBLK6, 128, 0, stream>>>(S, T, AfragW, AfragMS2, c1f, rw2, rb2, slearn, partial);
    score_kernel<<<1, 256, 0, stream>>>(partial, ep, scoreBuf);
    softmax_kernel<<<288, 256, 0, stream>>>(slearn, scoreBuf, out);
}